// Round 8
// baseline (119.471 us; speedup 1.0000x reference)
//
#include <hip/hip_runtime.h>
#include <hip/hip_bf16.h>

#define NB 4
#define SS 1024
#define DIN 768
#define NH 12
#define DH 64

typedef float f32x4 __attribute__((ext_vector_type(4)));
typedef short bf16x8 __attribute__((ext_vector_type(8)));

static __device__ __forceinline__ unsigned short f2bf(float f) {
    __hip_bfloat16 h = __float2bfloat16(f);
    return *reinterpret_cast<unsigned short*>(&h);
}

static __device__ __forceinline__ float exp2_fast(float x) {
    return __builtin_amdgcn_exp2f(x);   // v_exp_f32: 2^x
}

static __device__ __forceinline__ void gload16(const void* g, void* l) {
    __builtin_amdgcn_global_load_lds(
        (const __attribute__((address_space(1))) void*)g,
        (__attribute__((address_space(3))) void*)l, 16, 0, 0);
}

// ---------- kernel 1: prep = cast x -> bf16  +  transpose W -> wt (fused) ----------
__global__ void prep_kernel(const float* __restrict__ x, const float* __restrict__ Wq,
                            const float* __restrict__ Wk, const float* __restrict__ Wv,
                            unsigned short* __restrict__ xb, unsigned short* __restrict__ wt) {
    __shared__ float lds[64][68];
    int bid = blockIdx.x, tid = threadIdx.x;
    {
        int i = (bid * 256 + tid) * 4;
        float4 v = *reinterpret_cast<const float4*>(x + i);
        ushort4 o;
        o.x = f2bf(v.x); o.y = f2bf(v.y); o.z = f2bf(v.z); o.w = f2bf(v.w);
        *reinterpret_cast<ushort4*>(xb + i) = o;
    }
    if (bid < 432) {
        int d0 = (bid % 12) * 64, h = (bid / 12) % 12, p = bid / 144;
        const float* W = (p == 0) ? Wq : (p == 1) ? Wk : Wv;
        const float* base = W + (size_t)h * DIN * DH;   // [768][64]
        int rr = tid >> 4, c4 = tid & 15;
#pragma unroll
        for (int i = 0; i < 4; ++i) {
            int d = i * 16 + rr;
            float4 v = *reinterpret_cast<const float4*>(base + (size_t)(d0 + d) * DH + c4 * 4);
            lds[d][c4 * 4 + 0] = v.x; lds[d][c4 * 4 + 1] = v.y;
            lds[d][c4 * 4 + 2] = v.z; lds[d][c4 * 4 + 3] = v.w;
        }
        __syncthreads();
        unsigned short* outp = wt + ((size_t)(p * NH + h) * DH) * DIN;
#pragma unroll
        for (int i = 0; i < 4; ++i) {
            int e = i * 16 + rr;
            int dc = c4 * 4;
            ushort4 o;
            o.x = f2bf(lds[dc + 0][e]); o.y = f2bf(lds[dc + 1][e]);
            o.z = f2bf(lds[dc + 2][e]); o.w = f2bf(lds[dc + 3][e]);
            *reinterpret_cast<ushort4*>(outp + (size_t)e * DIN + d0 + dc) = o;
        }
    }
}

// ---- kernel 2: QKV GEMM, double-buffered LDS, ONE barrier per K-step (T3-min).
// ---- Tile 128x96, grid 768 (XCD-swizzled). LDS: a0|a1 [0,32768), b0|b1 [32768,57344)
__global__ __launch_bounds__(256) void qkv_gemm_kernel(
    const unsigned short* __restrict__ xb, const unsigned short* __restrict__ wt,
    unsigned short* __restrict__ qb, unsigned short* __restrict__ kb,
    unsigned short* __restrict__ vT) {
    __shared__ __align__(16) unsigned char smem[57344];

    int sb = (blockIdx.x & 7) * 96 + (blockIdx.x >> 3);   // XCD swizzle (768%8==0)
    int m0 = (sb & 31) * 128;
    int n0 = (sb >> 5) * 96;
    int tid = threadIdx.x, lane = tid & 63, w = tid >> 6;
    int l15 = lane & 15, hi4 = (lane >> 4) * 4, hi8 = (lane >> 4) * 8;
    int wr = w >> 1, wc = w & 1;
    int srow = tid >> 3;            // 0..31
    int scolb = (tid & 7) * 16;     // byte col
    int sw = (l15 & 7) << 4;        // read-side XOR

    f32x4 acc[4][3] = {};

    // stage K-step k0 into buffer `buf`
    auto stage = [&](int buf, int k0) {
        unsigned short* al = (unsigned short*)(smem + buf * 16384);
        unsigned short* bl = (unsigned short*)(smem + 32768 + buf * 12288);
#pragma unroll
        for (int i = 0; i < 4; ++i) {
            int row = i * 32 + srow;
            int cb = scolb ^ ((row & 7) << 4);
            gload16(xb + (size_t)(m0 + row) * DIN + k0 + (cb >> 1), al + row * 64 + (scolb >> 1));
        }
#pragma unroll
        for (int i = 0; i < 3; ++i) {
            int row = i * 32 + srow;
            int cb = scolb ^ ((row & 7) << 4);
            gload16(wt + (size_t)(n0 + row) * DIN + k0 + (cb >> 1), bl + row * 64 + (scolb >> 1));
        }
    };

    stage(0, 0);
    __syncthreads();                      // drain prologue stage
    for (int t = 0; t < 12; ++t) {
        int cur = t & 1;
        if (t < 11) stage(cur ^ 1, (t + 1) * 64);    // issue next-tile DMA first
        const unsigned short* a_lds = (const unsigned short*)(smem + cur * 16384);
        const unsigned short* b_lds = (const unsigned short*)(smem + 32768 + cur * 12288);
#pragma unroll
        for (int kk = 0; kk < 64; kk += 32) {
            int cb = ((kk + hi8) * 2) ^ sw;
            bf16x8 af[4], bfr[3];
#pragma unroll
            for (int m = 0; m < 4; ++m)
                af[m] = *reinterpret_cast<const bf16x8*>(a_lds + (wr * 64 + m * 16 + l15) * 64 + (cb >> 1));
#pragma unroll
            for (int n = 0; n < 3; ++n)
                bfr[n] = *reinterpret_cast<const bf16x8*>(b_lds + (wc * 48 + n * 16 + l15) * 64 + (cb >> 1));
#pragma unroll
            for (int m = 0; m < 4; ++m)
#pragma unroll
                for (int n = 0; n < 3; ++n)
                    acc[m][n] = __builtin_amdgcn_mfma_f32_16x16x32_bf16(af[m], bfr[n], acc[m][n], 0, 0, 0);
        }
        __syncthreads();                  // next stage complete + reads of cur done
    }

    int p  = n0 / 768;
    int cp = (n0 % 768) + wc * 48;
    int b  = m0 >> 10;
    int s_base = (m0 & 1023) + wr * 64;

    if (p < 2) {
        float qs = (p == 0) ? 0.180336880f : 1.0f;   // 0.125*log2(e) folded into Q
        unsigned short* dstb = (p == 0) ? qb : kb;
#pragma unroll
        for (int m = 0; m < 4; ++m)
#pragma unroll
            for (int n = 0; n < 3; ++n)
#pragma unroll
                for (int r = 0; r < 4; ++r) {
                    int col = cp + n * 16 + l15;
                    int h = col >> 6, e = col & 63;
                    dstb[((size_t)(b * NH + h) * SS + s_base + m * 16 + hi4 + r) * DH + e] =
                        f2bf(acc[m][n][r] * qs);
                }
    } else {
        // V: per-wave 16x49 f32 strip transpose, store [b][h][e][t]
        float* sc = (float*)smem + w * 784;
#pragma unroll
        for (int m = 0; m < 4; ++m) {
#pragma unroll
            for (int n = 0; n < 3; ++n)
#pragma unroll
                for (int r = 0; r < 4; ++r)
                    sc[(hi4 + r) * 49 + n * 16 + l15] = acc[m][n][r];
            if (lane < 48) {
                unsigned short vv[16];
#pragma unroll
                for (int t2 = 0; t2 < 16; ++t2) vv[t2] = f2bf(sc[t2 * 49 + lane]);
                int col = cp + lane;
                int h = col >> 6, e = col & 63;
                unsigned short* dst = vT + ((size_t)(b * NH + h) * DH + e) * SS + s_base + m * 16;
                *reinterpret_cast<uint4*>(dst)     = *reinterpret_cast<const uint4*>(vv);
                *reinterpret_cast<uint4*>(dst + 8) = *reinterpret_cast<const uint4*>(vv + 8);
            }
        }
    }
}

// ---- kernel 3: causal flash attention, swapped-operand softmax-in-lane.
// LDS = 40960 B exactly -> 4 blocks/CU. Magic-triple bid->qi decode balances
// per-CU work under round-robin dispatch (triples sum 22-23 steps).
struct AttnCtx {
    const unsigned short* kg;
    const unsigned short* vg;
    char* smem;
    unsigned short* pw;
    int srow, scolb, l15, hi, sw;
};

static __device__ __forceinline__ void attn_stage(const AttnCtx& c, int buf, int kv) {
    unsigned short* kl = (unsigned short*)(c.smem + buf * 8192);
    unsigned short* vl = (unsigned short*)(c.smem + 16384 + buf * 8192);
#pragma unroll
    for (int i = 0; i < 2; ++i) {
        int row = i * 32 + c.srow;
        int cb = c.scolb ^ ((row & 7) << 4);
        gload16(c.kg + (size_t)(kv * 64 + row) * DH + (cb >> 1), kl + row * 64 + (c.scolb >> 1));
        gload16(c.vg + (size_t)row * SS + kv * 64 + (cb >> 1),   vl + row * 64 + (c.scolb >> 1));
    }
}

template<bool DIAG>
static __device__ __forceinline__ void attn_step(
    const AttnCtx& c, int buf, int kv, int qg,
    bf16x8 qf0, bf16x8 qf1, float& m_r, float& l_r, f32x4 o_acc[4]) {
    const unsigned short* kl = (const unsigned short*)(c.smem + buf * 8192);
    const unsigned short* vl = (const unsigned short*)(c.smem + 16384 + buf * 8192);
    int l15 = c.l15, hi = c.hi, sw = c.sw;
    int hi4 = hi * 4, hi8 = hi * 8;

    // QK^T swapped: sacc[n] = C[kv_local = 16n+hi4+r][q = l15]
    f32x4 sacc[4] = {};
    __builtin_amdgcn_s_setprio(1);
#pragma unroll
    for (int s = 0; s < 2; ++s) {
        int cb = ((32 * s + hi8) * 2) ^ sw;
#pragma unroll
        for (int n = 0; n < 4; ++n) {
            bf16x8 kf = *reinterpret_cast<const bf16x8*>(kl + (16 * n + l15) * 64 + (cb >> 1));
            sacc[n] = __builtin_amdgcn_mfma_f32_16x16x32_bf16(kf, s == 0 ? qf0 : qf1, sacc[n], 0, 0, 0);
        }
    }
    __builtin_amdgcn_s_setprio(0);

    float pv[4][4];
#pragma unroll
    for (int n = 0; n < 4; ++n)
#pragma unroll
        for (int r = 0; r < 4; ++r) {
            float sv = sacc[n][r];
            if (DIAG && (kv * 64 + 16 * n + hi4 + r) > qg) sv = -INFINITY;
            pv[n][r] = sv;
        }

    // in-lane row softmax (lane owns q = qg; cross-hi via 2 shfl)
    float mn[4];
#pragma unroll
    for (int n = 0; n < 4; ++n)
        mn[n] = fmaxf(fmaxf(pv[n][0], pv[n][1]), fmaxf(pv[n][2], pv[n][3]));
    float mx = fmaxf(fmaxf(mn[0], mn[1]), fmaxf(mn[2], mn[3]));
    mx = fmaxf(mx, __shfl_xor(mx, 16));
    mx = fmaxf(mx, __shfl_xor(mx, 32));

    // defer-max (T13)
    if (!__all(mx - m_r <= 8.0f)) {
        float m_new = fmaxf(m_r, mx);
        float alpha = exp2_fast(m_r - m_new);
        l_r *= alpha;
#pragma unroll
        for (int n = 0; n < 4; ++n)
#pragma unroll
            for (int r = 0; r < 4; ++r) o_acc[n][r] *= alpha;
        m_r = m_new;
    }
    float sn[4];
#pragma unroll
    for (int n = 0; n < 4; ++n) {
#pragma unroll
        for (int r = 0; r < 4; ++r) pv[n][r] = exp2_fast(pv[n][r] - m_r);
        sn[n] = (pv[n][0] + pv[n][1]) + (pv[n][2] + pv[n][3]);
    }
    float sum = (sn[0] + sn[1]) + (sn[2] + sn[3]);
    sum += __shfl_xor(sum, 16);
    sum += __shfl_xor(sum, 32);
    l_r += sum;

    // P^T -> swizzled stride-64 LDS (row q=l15, u32 idx (8n+2hi+p2)^xr)
    int xr = (l15 & 7) * 4;
    unsigned int* pwu = (unsigned int*)c.pw;
#pragma unroll
    for (int n = 0; n < 4; ++n)
#pragma unroll
        for (int p2 = 0; p2 < 2; ++p2) {
            unsigned int w32 = (unsigned int)f2bf(pv[n][2 * p2]) |
                               ((unsigned int)f2bf(pv[n][2 * p2 + 1]) << 16);
            pwu[l15 * 32 + ((8 * n + 2 * hi + p2) ^ xr)] = w32;
        }
    int i0 = (4 * hi) ^ xr;          // u32 base for kv 8hi..8hi+7
    int i1 = (16 + 4 * hi) ^ xr;     // u32 base for kv 32+8hi..32+8hi+7
    bf16x8 pa0 = *reinterpret_cast<const bf16x8*>(c.pw + l15 * 64 + i0 * 2);
    bf16x8 pa1 = *reinterpret_cast<const bf16x8*>(c.pw + l15 * 64 + i1 * 2);

    // O^T += V^T . P^T : o_acc[n] = C[e = 16n+hi4+r][q = l15]
    __builtin_amdgcn_s_setprio(1);
#pragma unroll
    for (int s = 0; s < 2; ++s) {
        int cb = ((32 * s + hi8) * 2) ^ sw;
#pragma unroll
        for (int n = 0; n < 4; ++n) {
            bf16x8 vf = *reinterpret_cast<const bf16x8*>(vl + (16 * n + l15) * 64 + (cb >> 1));
            o_acc[n] = __builtin_amdgcn_mfma_f32_16x16x32_bf16(vf, s == 0 ? pa0 : pa1, o_acc[n], 0, 0, 0);
        }
    }
    __builtin_amdgcn_s_setprio(0);
}

__global__ __launch_bounds__(256, 4) void attn_kernel(
    const unsigned short* __restrict__ qb, const unsigned short* __restrict__ kb,
    const unsigned short* __restrict__ vT, float* __restrict__ out) {
    __shared__ __align__(16) char smem[40960];

    // magic-triple decode: CU c's blocks (c, c+256, c+512) get qi summing 22-23
    int bid = blockIdx.x;
    int cc = bid & 255, j = bid >> 8;
    int u = cc >> 4, v = cc & 15;
    int qi = (j == 0) ? u : ((j == 1) ? 15 - (u >> 1) : 7 - (u >> 1));
    int idx = (j == 0) ? v : (16 + 16 * (u & 1) + v);
    int h = idx % 12, b = idx / 12;
    int q0 = qi * 64;
    int tid = threadIdx.x, lane = tid & 63, w = tid >> 6;
    int l15 = lane & 15, hi = lane >> 4;
    int hi4 = hi * 4, hi8 = hi * 8;
    size_t bh = (size_t)(b * NH + h);

    AttnCtx c;
    c.kg = kb + bh * SS * DH;
    c.vg = vT + bh * DH * SS;
    c.smem = smem;
    c.pw = (unsigned short*)(smem + 32768) + w * 1024;
    c.srow = tid >> 3; c.scolb = (tid & 7) * 16;
    c.l15 = l15; c.hi = hi; c.sw = (l15 & 7) << 4;

    int qg = q0 + 16 * w + l15;
    const unsigned short* qp = qb + (bh * SS + qg) * DH;
    bf16x8 qf0 = *reinterpret_cast<const bf16x8*>(qp + hi8);
    bf16x8 qf1 = *reinterpret_cast<const bf16x8*>(qp + 32 + hi8);

    float m_r = -INFINITY, l_r = 0.f;
    f32x4 o_acc[4] = {};

    attn_stage(c, 0, 0);
    __syncthreads();
    for (int kv = 0; kv < qi; ++kv) {
        attn_stage(c, (kv & 1) ^ 1, kv + 1);       // overlap next-tile DMA with compute
        attn_step<false>(c, kv & 1, kv, qg, qf0, qf1, m_r, l_r, o_acc);
        __syncthreads();
    }
    attn_step<true>(c, qi & 1, qi, qg, qf0, qf1, m_r, l_r, o_acc);
    __syncthreads();   // before LDS scratch reuse

    // epilogue: O^T -> per-wave LDS strip -> coalesced float4 stores
    float inv = 1.f / l_r;
    float* sc = (float*)(smem + w * 4352);         // [16 q][68 e]
#pragma unroll
    for (int n = 0; n < 4; ++n)
#pragma unroll
        for (int r = 0; r < 4; ++r)
            sc[l15 * 68 + 16 * n + hi4 + r] = o_acc[n][r] * inv;
    __builtin_amdgcn_s_waitcnt(0);                 // lgkm drain (wave-private strip)
#pragma unroll
    for (int jj = 0; jj < 4; ++jj) {
        f32x4 vv = *reinterpret_cast<const f32x4*>(sc + l15 * 68 + jj * 16 + hi4);
        *reinterpret_cast<f32x4*>(out + ((size_t)b * SS + q0 + 16 * w + l15) * (NH * DH)
                                  + h * DH + jj * 16 + hi4) = vv;
    }
}

extern "C" void kernel_launch(void* const* d_in, const int* in_sizes, int n_in,
                              void* d_out, int out_size, void* d_ws, size_t ws_size,
                              hipStream_t stream) {
    const float* x  = (const float*)d_in[0];
    const float* Wq = (const float*)d_in[1];
    const float* Wk = (const float*)d_in[2];
    const float* Wv = (const float*)d_in[3];
    float* out = (float*)d_out;

    char* ws = (char*)d_ws;
    unsigned short* xb = (unsigned short*)ws;                   //  6,291,456 B
    unsigned short* wt = (unsigned short*)(ws +  6291456);      //  3,538,944 B
    unsigned short* qb = (unsigned short*)(ws +  9830400);      //  6,291,456 B
    unsigned short* kb = (unsigned short*)(ws + 16121856);      //  6,291,456 B
    unsigned short* vT = (unsigned short*)(ws + 22413312);      //  6,291,456 B

    hipLaunchKernelGGL(prep_kernel,     dim3(3072), dim3(256), 0, stream, x, Wq, Wk, Wv, xb, wt);
    hipLaunchKernelGGL(qkv_gemm_kernel, dim3(768),  dim3(256), 0, stream, xb, wt, qb, kb, vT);
    hipLaunchKernelGGL(attn_kernel,     dim3(768),  dim3(256), 0, stream, qb, kb, vT, out);
}